// Round 1
// 826.817 us; speedup vs baseline: 1.0169x; 1.0169x over previous
//
#include <hip/hip_runtime.h>
#include <hip/hip_fp16.h>

#define N_IN   1000000
#define N_OUT  250000
#define KOFF   8
#define PPAIR  125000
#define NPAIR  1000000          // KOFF * PPAIR
#define C_IN   64
#define C_OUT  128
#define BN_EPS 1e-5f

typedef __attribute__((ext_vector_type(8))) short short8;
typedef __attribute__((ext_vector_type(4))) float floatx4;

// float -> bf16 with round-to-nearest-even
__device__ __forceinline__ unsigned short f2bf(float x) {
    unsigned u = __float_as_uint(x);
    unsigned r = u + 0x7FFF + ((u >> 16) & 1);
    return (unsigned short)(r >> 16);
}

// ---------------------------------------------------------------------------
// Kernel 0: pack W[k][i][n] fp32 -> Wpack[k][n][i] bf16 (K-major per column).
// ---------------------------------------------------------------------------
__global__ __launch_bounds__(256) void pack_w(
    const float* __restrict__ W, unsigned short* __restrict__ wp)
{
    int e = blockIdx.x * 256 + threadIdx.x;          // e < 8*64*128 = 65536
    int k = e >> 13;
    int rem = e & 8191;
    int i = rem >> 7;                                // input channel (K)
    int n = rem & 127;                               // output channel (N)
    wp[k * 8192 + n * 64 + i] = f2bf(W[e]);
}

// ---------------------------------------------------------------------------
// CSR build: histogram of out_idx -> exclusive scan -> row_ptr + cursor.
// Replaces 64M fp16 RMW atomics with ~2M int atomics + plain stores.
// ---------------------------------------------------------------------------
__global__ __launch_bounds__(256) void k_count(
    const int* __restrict__ oidx, int* __restrict__ counts)
{
    int e = blockIdx.x * 256 + threadIdx.x;
    if (e < NPAIR) atomicAdd(&counts[oidx[e]], 1);
}

__global__ __launch_bounds__(1024) void k_scanA(
    const int* __restrict__ counts, int* __restrict__ rp, int* __restrict__ bsum)
{
    __shared__ int ls[1024];
    const int tid = threadIdx.x;
    const int i = blockIdx.x * 1024 + tid;
    int v = (i < N_OUT) ? counts[i] : 0;
    ls[tid] = v;
    __syncthreads();
    for (int d = 1; d < 1024; d <<= 1) {             // Hillis-Steele inclusive
        int t = (tid >= d) ? ls[tid - d] : 0;
        __syncthreads();
        ls[tid] += t;
        __syncthreads();
    }
    if (i < N_OUT) rp[i] = ls[tid] - v;              // exclusive, partial
    if (tid == 1023) bsum[blockIdx.x] = ls[1023];
}

__global__ __launch_bounds__(256) void k_scanB(int* __restrict__ bsum)
{
    __shared__ int ls[256];
    const int tid = threadIdx.x;
    int v = bsum[tid];
    ls[tid] = v;
    __syncthreads();
    for (int d = 1; d < 256; d <<= 1) {
        int t = (tid >= d) ? ls[tid - d] : 0;
        __syncthreads();
        ls[tid] += t;
        __syncthreads();
    }
    bsum[tid] = ls[tid] - v;                         // exclusive block offsets
}

__global__ __launch_bounds__(1024) void k_scanC(
    int* __restrict__ rp, const int* __restrict__ bsum, int* __restrict__ cursor)
{
    const int i = blockIdx.x * 1024 + threadIdx.x;
    if (i < N_OUT) {
        int r = rp[i] + bsum[blockIdx.x];
        rp[i] = r;
        cursor[i] = r;                               // rank cursors start at row_ptr
    }
    if (blockIdx.x == 0 && threadIdx.x == 0) rp[N_OUT] = NPAIR;
}

// ---------------------------------------------------------------------------
// Kernel 1: MFMA gather-GEMM. One wave = 16 pairs x 128 channels via 16x
// mfma_f32_16x16x32_bf16. Scatter variants:
//  MODE 2: CSR store — each pair claims a unique slot (atomicAdd on int
//          cursor, 1 per pair = 16/wave) and writes its 128-ch contribution
//          with PLAIN packed-fp16 stores. No fp16 RMW atomics at all.
//  MODE 1: packed fp16 atomics into hacc (fallback, previous behavior).
//  MODE 0: fp32 atomics into d_out (small-ws fallback).
// ---------------------------------------------------------------------------
template <int MODE>
__global__ __launch_bounds__(256) void scatter_mfma(
    const float*          __restrict__ feat,
    const unsigned short* __restrict__ wpack,
    const int*            __restrict__ in_idx,
    const int*            __restrict__ out_idx,
    __half*               __restrict__ hacc,
    float*                __restrict__ facc,
    int*                  __restrict__ cursor,
    __half*               __restrict__ contrib)
{
    const int lane = threadIdx.x & 63;
    const int wave = threadIdx.x >> 6;               // 0..3
    const int quad = lane >> 4;                      // 0..3
    const int col  = lane & 15;
    const int k    = blockIdx.y;
    const int base = blockIdx.x * 64 + wave * 16;    // first pair of this wave

    // ---- A fragments (2 K-steps) ----
    const int gp_a = base + col;                     // pair this lane supplies
    const int iid  = (gp_a < PPAIR) ? in_idx[k * PPAIR + gp_a] : 0;
    const float* frow = feat + (long)iid * C_IN;

    short8 afrag[2];
#pragma unroll
    for (int s = 0; s < 2; ++s) {
        const float4 f0 = *(const float4*)(frow + s * 32 + quad * 8);
        const float4 f1 = *(const float4*)(frow + s * 32 + quad * 8 + 4);
        short8 a;
        a[0] = (short)f2bf(f0.x); a[1] = (short)f2bf(f0.y);
        a[2] = (short)f2bf(f0.z); a[3] = (short)f2bf(f0.w);
        a[4] = (short)f2bf(f1.x); a[5] = (short)f2bf(f1.y);
        a[6] = (short)f2bf(f1.z); a[7] = (short)f2bf(f1.w);
        afrag[s] = a;
    }

    // ---- MODE 2: claim CSR slots early so atomic latency hides under MFMA ----
    int myrank = 0;
    if (MODE == 2) {
        const int gp = base + lane;
        if (lane < 16 && gp < PPAIR) {
            const int o = out_idx[k * PPAIR + gp];
            myrank = atomicAdd(&cursor[o], 1);       // unique slot for this pair
        }
    }

    // ---- B fragments: Wpack[k][n= t*16+col][ s*32 + quad*8 + 0..7 ] ----
    const unsigned short* wk = wpack + k * 8192;
    short8 bfrag[2][8];
#pragma unroll
    for (int s = 0; s < 2; ++s)
#pragma unroll
        for (int t = 0; t < 8; ++t)
            bfrag[s][t] = *(const short8*)(wk + (t * 16 + col) * 64 + s * 32 + quad * 8);

    // ---- 16 MFMAs ----
    floatx4 acc[8];
#pragma unroll
    for (int t = 0; t < 8; ++t) acc[t] = (floatx4){0.f, 0.f, 0.f, 0.f};
#pragma unroll
    for (int s = 0; s < 2; ++s)
#pragma unroll
        for (int t = 0; t < 8; ++t)
            acc[t] = __builtin_amdgcn_mfma_f32_16x16x32_bf16(
                afrag[s], bfrag[s][t], acc[t], 0, 0, 0);

    // ---- scatter ----
    if (MODE == 2) {
        // C/D layout: col(N)=lane&15, row(M)=quad*4+r. Pair channels via
        // shfl_xor(1), even cols store __half2 -> 4B plain stores, full rows
        // of 256B per pair slot; L2 merges into full lines (no RMW).
#pragma unroll
        for (int r = 0; r < 4; ++r) {
            const int row  = quad * 4 + r;
            const int p    = __shfl(myrank, row);    // slot of pair base+row
            const bool vld = (base + row) < PPAIR;
#pragma unroll
            for (int t = 0; t < 8; ++t) {
                const float v = acc[t][r];
                const float w = __shfl_xor(v, 1, 64);
                if (vld && !(lane & 1)) {
                    const __half2 h = __halves2half2(__float2half(v), __float2half(w));
                    *reinterpret_cast<__half2*>(contrib + (long)p * C_OUT + t * 16 + col) = h;
                }
            }
        }
    } else {
        int oid[4];
#pragma unroll
        for (int r = 0; r < 4; ++r) {
            const int gp = base + quad * 4 + r;      // row m = quad*4+r
            oid[r] = (gp < PPAIR) ? out_idx[k * PPAIR + gp] : -1;
        }
        if (MODE == 1) {
#pragma unroll
            for (int t = 0; t < 8; ++t)
#pragma unroll
                for (int r = 0; r < 4; ++r) {
                    const float v = acc[t][r];
                    const float w = __shfl_xor(v, 1, 64);
                    if (oid[r] >= 0 && !(lane & 1)) {
                        const __half2 h = __halves2half2(__float2half(v), __float2half(w));
                        unsafeAtomicAdd((__half2*)(hacc + (long)oid[r] * C_OUT + t * 16 + col), h);
                    }
                }
        } else {
#pragma unroll
            for (int t = 0; t < 8; ++t)
#pragma unroll
                for (int r = 0; r < 4; ++r)
                    if (oid[r] >= 0)
                        atomicAdd(facc + (long)oid[r] * C_OUT + t * 16 + col, acc[t][r]);
        }
    }
}

// ---------------------------------------------------------------------------
// Segmented reduce: contributions of out row r occupy contrib[rp[r]..rp[r+1])
// contiguously, so this is a sequential 256MB scan. Fuses BN sum/sumsq.
// One wave per out row (64 lanes x half2 = 128 channels), rows striped so
// the 8192 concurrent waves cover a contiguous ~8MB window.
// ---------------------------------------------------------------------------
__global__ __launch_bounds__(256) void k_reduce(
    const __half* __restrict__ contrib,
    const int*    __restrict__ rp,
    float*        __restrict__ out,
    float*        __restrict__ sums)
{
    const int lane = threadIdx.x & 63;
    const int wv   = threadIdx.x >> 6;
    const int gw   = blockIdx.x * 4 + wv;
    const int NW   = gridDim.x * 4;
    float s0 = 0.f, s1 = 0.f, q0 = 0.f, q1 = 0.f;
    for (int r = gw; r < N_OUT; r += NW) {
        const int b = rp[r], e = rp[r + 1];
        float a0 = 0.f, a1 = 0.f;
        for (int j = b; j < e; ++j) {
            const __half2 h = ((const __half2*)contrib)[(long)j * 64 + lane];
            const float2 f = __half22float2(h);
            a0 += f.x; a1 += f.y;
        }
        ((float2*)out)[(long)r * 64 + lane] = make_float2(a0, a1);
        s0 += a0; s1 += a1;
        q0 = fmaf(a0, a0, q0); q1 = fmaf(a1, a1, q1);
    }
    __shared__ float4 ls[256];
    ls[threadIdx.x] = make_float4(s0, s1, q0, q1);
    __syncthreads();
    if (wv == 0) {
        float4 a = ls[lane], b = ls[64 + lane], c = ls[128 + lane], d = ls[192 + lane];
        atomicAdd(&sums[2 * lane],           a.x + b.x + c.x + d.x);
        atomicAdd(&sums[2 * lane + 1],       a.y + b.y + c.y + d.y);
        atomicAdd(&sums[128 + 2 * lane],     a.z + b.z + c.z + d.z);
        atomicAdd(&sums[128 + 2 * lane + 1], a.w + b.w + c.w + d.w);
    }
}

// ---------------------------------------------------------------------------
// BN stats (fp16 accum fallback path): per-channel sum / sumsq.
// ---------------------------------------------------------------------------
__global__ __launch_bounds__(256) void bn_stats_h(
    const __half* __restrict__ hacc, float* __restrict__ sums)
{
    const int c2 = threadIdx.x & 63;
    const int g  = threadIdx.x >> 6;
    float s0 = 0.f, s1 = 0.f, q0 = 0.f, q1 = 0.f;
    for (int r = blockIdx.x * 4 + g; r < N_OUT; r += gridDim.x * 4) {
        const __half2 h = ((const __half2*)hacc)[(long)r * 64 + c2];
        const float2 f = __half22float2(h);
        s0 += f.x; s1 += f.y;
        q0 = fmaf(f.x, f.x, q0); q1 = fmaf(f.y, f.y, q1);
    }
    __shared__ float4 ls[256];
    ls[threadIdx.x] = make_float4(s0, s1, q0, q1);
    __syncthreads();
    if (g == 0) {
        float4 a = ls[c2], b = ls[64 + c2], c = ls[128 + c2], d = ls[192 + c2];
        atomicAdd(&sums[2 * c2],           a.x + b.x + c.x + d.x);
        atomicAdd(&sums[2 * c2 + 1],       a.y + b.y + c.y + d.y);
        atomicAdd(&sums[128 + 2 * c2],     a.z + b.z + c.z + d.z);
        atomicAdd(&sums[128 + 2 * c2 + 1], a.w + b.w + c.w + d.w);
    }
}

// BN stats (fp32 fallback, reads d_out in place)
__global__ __launch_bounds__(512) void bn_stats_f(
    const float* __restrict__ out, float* __restrict__ sums)
{
    const int c = threadIdx.x & 127;
    const int g = threadIdx.x >> 7;
    float s = 0.f, q = 0.f;
    for (int r = blockIdx.x * 4 + g; r < N_OUT; r += gridDim.x * 4) {
        const float x = out[(long)r * C_OUT + c];
        s += x; q = fmaf(x, x, q);
    }
    __shared__ float ls[512], lq[512];
    ls[threadIdx.x] = s; lq[threadIdx.x] = q;
    __syncthreads();
    if (g == 0) {
        atomicAdd(&sums[c],       ls[c] + ls[128 + c] + ls[256 + c] + ls[384 + c]);
        atomicAdd(&sums[128 + c], lq[c] + lq[128 + c] + lq[256 + c] + lq[384 + c]);
    }
}

__global__ __launch_bounds__(128) void bn_finalize(
    const float* __restrict__ sums,
    const float* __restrict__ gamma,
    const float* __restrict__ beta,
    float*       __restrict__ ss)
{
    const int c = threadIdx.x;
    const float inv_n = 1.0f / (float)N_OUT;
    const float mean  = sums[c] * inv_n;
    const float var   = sums[128 + c] * inv_n - mean * mean;
    const float sc    = gamma[c] * rsqrtf(var + BN_EPS);
    ss[c]       = sc;
    ss[128 + c] = fmaf(-mean, sc, beta[c]);
}

// BN apply (fp16 accum -> fp32 out, fallback)
__global__ __launch_bounds__(256) void bn_apply_h(
    const __half* __restrict__ hacc,
    const float*  __restrict__ ss,
    float*        __restrict__ out)
{
    const long j = (long)blockIdx.x * 256 + threadIdx.x;   // float4 index
    const __half2 h0 = ((const __half2*)hacc)[j * 2];
    const __half2 h1 = ((const __half2*)hacc)[j * 2 + 1];
    const float2 f0 = __half22float2(h0);
    const float2 f1 = __half22float2(h1);
    const int c = ((int)j & 31) * 4;
    float4 v;
    v.x = fmaxf(0.f, fmaf(f0.x, ss[c + 0], ss[128 + c + 0]));
    v.y = fmaxf(0.f, fmaf(f0.y, ss[c + 1], ss[128 + c + 1]));
    v.z = fmaxf(0.f, fmaf(f1.x, ss[c + 2], ss[128 + c + 2]));
    v.w = fmaxf(0.f, fmaf(f1.y, ss[c + 3], ss[128 + c + 3]));
    ((float4*)out)[j] = v;
}

// BN apply (fp32 in place)
__global__ __launch_bounds__(256) void bn_apply_f(
    float* __restrict__ out, const float* __restrict__ ss)
{
    const long j = (long)blockIdx.x * 256 + threadIdx.x;
    const int c = ((int)j & 31) * 4;
    float4 v = ((const float4*)out)[j];
    v.x = fmaxf(0.f, fmaf(v.x, ss[c + 0], ss[128 + c + 0]));
    v.y = fmaxf(0.f, fmaf(v.y, ss[c + 1], ss[128 + c + 1]));
    v.z = fmaxf(0.f, fmaf(v.z, ss[c + 2], ss[128 + c + 2]));
    v.w = fmaxf(0.f, fmaf(v.w, ss[c + 3], ss[128 + c + 3]));
    ((float4*)out)[j] = v;
}

// ---------------------------------------------------------------------------
extern "C" void kernel_launch(void* const* d_in, const int* in_sizes, int n_in,
                              void* d_out, int out_size, void* d_ws, size_t ws_size,
                              hipStream_t stream)
{
    const float* feat    = (const float*)d_in[0];
    const float* weight  = (const float*)d_in[1];
    const float* gamma   = (const float*)d_in[2];
    const float* beta    = (const float*)d_in[3];
    const int*   in_idx  = (const int*)  d_in[4];
    const int*   out_idx = (const int*)  d_in[5];
    float* out = (float*)d_out;
    char* wsb = (char*)d_ws;

    // ---- MODE 2 (CSR) workspace layout ----
    const size_t CONTRIB_BYTES = (size_t)NPAIR * C_OUT * sizeof(__half); // 256 MB
    const size_t OFF_RP   = CONTRIB_BYTES;            // int[N_OUT+1]  (1 MB slot)
    const size_t OFF_CUR  = OFF_RP   + 1048576;       // int[N_OUT]
    const size_t OFF_CNT  = OFF_CUR  + 1048576;       // int[N_OUT]
    const size_t OFF_BS   = OFF_CNT  + 1048576;       // int[256]
    const size_t OFF_SUM  = OFF_BS   + 4096;          // float[256]
    const size_t OFF_SS   = OFF_SUM  + 1024;          // float[256]
    const size_t OFF_WP   = OFF_SS   + 1024;          // ushort[65536]
    const size_t NEED2    = OFF_WP + 131072;          // ~259.1 MB

    // ---- MODE 1 (fp16-atomic) workspace needs ----
    const size_t HACC_BYTES = (size_t)N_OUT * C_OUT * sizeof(__half);    // 64 MB
    const size_t NEED1 = HACC_BYTES + 1024 + 1024 + 131072;

    const int nblk_apply = (int)((long)N_OUT * C_OUT / 4 / 256);         // 31250
    dim3 g1((PPAIR + 63) / 64, KOFF);

    if (ws_size >= NEED2) {
        // =============== CSR path: no fp16 atomics ===============
        __half* contrib = (__half*)wsb;
        int*    rp      = (int*)(wsb + OFF_RP);
        int*    cursor  = (int*)(wsb + OFF_CUR);
        int*    counts  = (int*)(wsb + OFF_CNT);
        int*    bsum    = (int*)(wsb + OFF_BS);
        float*  sums    = (float*)(wsb + OFF_SUM);
        float*  ss      = (float*)(wsb + OFF_SS);
        unsigned short* wpack = (unsigned short*)(wsb + OFF_WP);

        hipMemsetAsync(counts, 0, (size_t)N_OUT * sizeof(int), stream);
        hipMemsetAsync(sums, 0, 256 * sizeof(float), stream);

        pack_w<<<256, 256, 0, stream>>>(weight, wpack);
        k_count<<<(NPAIR + 255) / 256, 256, 0, stream>>>(out_idx, counts);
        k_scanA<<<256, 1024, 0, stream>>>(counts, rp, bsum);
        k_scanB<<<1, 256, 0, stream>>>(bsum);
        k_scanC<<<256, 1024, 0, stream>>>(rp, bsum, cursor);
        scatter_mfma<2><<<g1, 256, 0, stream>>>(feat, wpack, in_idx, out_idx,
                                                nullptr, out, cursor, contrib);
        k_reduce<<<2048, 256, 0, stream>>>(contrib, rp, out, sums);
        bn_finalize<<<1, 128, 0, stream>>>(sums, gamma, beta, ss);
        bn_apply_f<<<nblk_apply, 256, 0, stream>>>(out, ss);
    } else if (ws_size >= NEED1) {
        // =============== fallback: packed fp16 atomics (previous best) ===============
        __half* hacc = (__half*)wsb;
        float*  sums = (float*)(wsb + HACC_BYTES);
        unsigned short* wpack = (unsigned short*)(wsb + HACC_BYTES + 1024);
        float*  ss   = (float*)((char*)wpack + 131072);

        hipMemsetAsync(hacc, 0, HACC_BYTES, stream);
        hipMemsetAsync(sums, 0, 256 * sizeof(float), stream);
        pack_w<<<256, 256, 0, stream>>>(weight, wpack);
        scatter_mfma<1><<<g1, 256, 0, stream>>>(feat, wpack, in_idx, out_idx,
                                                hacc, out, nullptr, nullptr);
        bn_stats_h<<<256, 256, 0, stream>>>(hacc, sums);
        bn_finalize<<<1, 128, 0, stream>>>(sums, gamma, beta, ss);
        bn_apply_h<<<nblk_apply, 256, 0, stream>>>(hacc, ss, out);
    } else {
        // =============== minimal-ws fallback: fp32 atomics ===============
        float* sums = (float*)wsb;
        unsigned short* wpack = (unsigned short*)(wsb + 1024);
        float* ss = (float*)(wsb + 1024 + 131072);

        hipMemsetAsync(out, 0, (size_t)N_OUT * C_OUT * sizeof(float), stream);
        hipMemsetAsync(sums, 0, 256 * sizeof(float), stream);
        pack_w<<<256, 256, 0, stream>>>(weight, wpack);
        scatter_mfma<0><<<g1, 256, 0, stream>>>(feat, wpack, in_idx, out_idx,
                                                nullptr, out, nullptr, nullptr);
        bn_stats_f<<<256, 512, 0, stream>>>(out, sums);
        bn_finalize<<<1, 128, 0, stream>>>(sums, gamma, beta, ss);
        bn_apply_f<<<nblk_apply, 256, 0, stream>>>(out, ss);
    }
}